// Round 1
// 199.942 us; speedup vs baseline: 1.0333x; 1.0333x over previous
//
#include <hip/hip_runtime.h>
#include <hip/hip_bf16.h>

// Problem constants
#define TT   20
#define TS   19          // T-1 steps
#define BB   16
#define HH   128
#define WW   128
#define CINN 2
#define CHN  64
#define NOUT 10
#define BETA 0.9f
#define INVB (1.0f / BETA)
#define THRV 1.0f

#define SPIKESUM_ELEMS (TS*BB*CHN)           // 19,456 ints
#define SPIKESUM_BYTES (SPIKESUM_ELEMS*4)    // 77,824 B
#define SR_IDX (BB*NOUT + TS*BB*NOUT)        // scalar spike-rate slot in out

#define LROWD  68                             // dwords per plane row (66 + 2 pad)
#define NPAIR  264                            // 4 rows x 66 pixel-pairs per t

typedef __attribute__((ext_vector_type(8))) short short8;
typedef __attribute__((ext_vector_type(4))) float float4v;
typedef __attribute__((ext_vector_type(4))) int   int4v;

// round-to-nearest-even fp32 -> bf16 bits (value in top 16 after +round)
__device__ __forceinline__ unsigned rne16(float f) {
    unsigned u = __float_as_uint(f);
    return (u + 0x7fffu + ((u >> 16) & 1u)) >> 16;
}
__device__ __forceinline__ float b2f(unsigned us) { return __uint_as_float(us << 16); }
__device__ __forceinline__ unsigned rndb(float f) {          // rounded bits, un-shifted
    unsigned u = __float_as_uint(f);
    return u + 0x7fffu + ((u >> 16) & 1u);
}
// hi/lo bf16 split of a pixel-pair, packed via v_perm (bit-identical to the
// old rne16-based pack, ~10 fewer VALU ops): hi word = {bf16(d1),bf16(d0)},
// lo word = {bf16(d1-hi1),bf16(d0-hi0)}.
__device__ __forceinline__ void pack2(float d0, float d1, unsigned &hi, unsigned &lo) {
    unsigned r0 = rndb(d0), r1 = rndb(d1);
    hi = __builtin_amdgcn_perm(r1, r0, 0x07060302u);
    float e0 = d0 - __uint_as_float(r0 & 0xffff0000u);
    float e1 = d1 - __uint_as_float(r1 & 0xffff0000u);
    lo = __builtin_amdgcn_perm(rndb(e1), rndb(e0), 0x07060302u);
}

// ---------------------------------------------------------------------------
// Fused flow-diff + 3x3 conv (bf16-split MFMA) + LIF scan + spike count.
//
// W-space LIF: store W_t = V_t / beta^t. Then the update is
//   W += (conv_t + bias) * beta^-t   (the MFMA C-operand IS the membrane),
//   spike iff W > ct,  W -= s*ct,   with ct = beta^-t.
// This deletes the per-element beta*V fma AND the accumulator zero-init.
// beta^-t folds into the A-pack (2 muls/thread/t) and the ct register.
// Bias rides the k=24 tap: A(q==3,elem0) = bf16-split(ct), B holds bias there.
// Spike counts are byte-packed (<=32/field) -> ONE pair of shfl_xor per t.
// t-loop explicitly unrolled x2 so LDS double-buffer addresses are static.
// ---------------------------------------------------------------------------
__global__ __launch_bounds__(256, 4) void lif_main(const float* __restrict__ x,
                                                   const float* __restrict__ w_conv,
                                                   const float* __restrict__ b_conv,
                                                   int* __restrict__ spikesum,
                                                   float* __restrict__ out) {
    __shared__ unsigned lds2[2][2][4 * LROWD];   // [buf][plane][row*68+dw] = 4352 B

    const float2* xp2 = (const float2*)x;        // pixel-granular (ci pair)
    const int FRAME2  = BB * HH * WW;            // float2s per time slice

    const int tid  = threadIdx.x;
    const int lane = tid & 63;
    const int wv   = __builtin_amdgcn_readfirstlane(tid >> 6); // uniform 0..3
    const int bx   = blockIdx.x;                 // 0..1 : pixel half
    const int r0   = blockIdx.y << 1;            // first of 2 output rows
    const int bz   = blockIdx.z;                 // batch
    const int q    = lane >> 4;                  // quad
    const int col  = lane & 15;
    const int relpx = (wv << 4) + col;           // 0..63 pixel within tile
    const int qsh  = q << 3;

    // zero the single cross-block-accumulated scalar (head atomics add later;
    // stream order lif -> head makes this safe). Replaces the d_out memset.
    if (bx == 0 && blockIdx.y == 0 && bz == 0 && tid == 0) out[SR_IDX] = 0.f;

    // ---- t-invariant staging slots (pair = one pixel, both ci)
    const int  pr0 = tid;
    const int  ra0r = pr0 / 66, ra0d = pr0 - ra0r * 66;
    const int  y0s  = r0 - 1 + ra0r;
    const int  px0s = (bx << 6) - 1 + ra0d;
    const bool val0 = ((unsigned)y0s < (unsigned)HH) && ((unsigned)px0s < (unsigned)WW);
    const int  off0 = val0 ? (y0s * WW + px0s) : 0;
    const int  ls0  = ra0r * LROWD + ra0d;

    const bool act1 = (tid < NPAIR - 256);
    const int  pr1 = 256 + tid;
    const int  ra1r = pr1 / 66, ra1d = pr1 - ra1r * 66;
    const int  y1s  = r0 - 1 + ra1r;
    const int  px1s = (bx << 6) - 1 + ra1d;
    const bool val1 = act1 && ((unsigned)y1s < (unsigned)HH) && ((unsigned)px1s < (unsigned)WW);
    const int  off1 = val1 ? (y1s * WW + px1s) : 0;
    const int  ls1  = ra1r * LROWD + ra1d;

    // ---- B fragments: k = q*8+j ; q<3,j<6: weights ; q==3,j==0 (k=24): bias
    short8 Bh[4], Bl[4];
#pragma unroll
    for (int cg = 0; cg < 4; ++cg) {
        int hi_i[4] = {0, 0, 0, 0}, lo_i[4] = {0, 0, 0, 0};
        if (q < 3) {
#pragma unroll
            for (int j = 0; j < 6; ++j) {
                float w = w_conv[((q * 3 + (j >> 1)) * 2 + (j & 1)) * CHN + cg * 16 + col];
                unsigned hs = rne16(w);
                unsigned ls = rne16(w - b2f(hs));
                hi_i[j >> 1] |= (int)(hs << (16 * (j & 1)));
                lo_i[j >> 1] |= (int)(ls << (16 * (j & 1)));
            }
        } else {
            float bb = b_conv[cg * 16 + col];
            unsigned hs = rne16(bb);
            unsigned ls = rne16(bb - b2f(hs));
            hi_i[0] = (int)hs;
            lo_i[0] = (int)ls;
        }
        int4v hv = {hi_i[0], hi_i[1], hi_i[2], hi_i[3]};
        int4v lv = {lo_i[0], lo_i[1], lo_i[2], lo_i[3]};
        Bh[cg] = __builtin_bit_cast(short8, hv);
        Bl[cg] = __builtin_bit_cast(short8, lv);
    }

    float4v W0[4], W1[4];                        // membrane (W-space), rows r0, r0+1
#pragma unroll
    for (int cg = 0; cg < 4; ++cg) {
        W0[cg] = (float4v){0.f, 0.f, 0.f, 0.f};
        W1[cg] = (float4v){0.f, 0.f, 0.f, 0.f};
    }

    float ct = 1.0f;                             // beta^-t, t=0
    int* spt = spikesum + bz * CHN + lane;

    // ---- preheader: rb = x[0], ra = x[1]
    float2 ra_0 = {0.f, 0.f}, rb_0 = {0.f, 0.f};
    float2 ra_1 = {0.f, 0.f}, rb_1 = {0.f, 0.f};
    {
        const int s2a = bz * HH * WW;
        if (val0) { rb_0 = xp2[s2a + off0]; ra_0 = xp2[s2a + FRAME2 + off0]; }
        if (val1) { rb_1 = xp2[s2a + off1]; ra_1 = xp2[s2a + FRAME2 + off1]; }
    }

#define STEP(T, BSEL) do {                                                      \
    const int t_ = (T);                                                         \
    unsigned* hiP = &lds2[BSEL][0][0];                                          \
    unsigned* loP = &lds2[BSEL][1][0];                                          \
    {                                                                           \
        float d0 = val0 ? (ra_0.x - rb_0.x) * ct : 0.f;                         \
        float d1 = val0 ? (ra_0.y - rb_0.y) * ct : 0.f;                         \
        unsigned hw, lw; pack2(d0, d1, hw, lw);                                 \
        hiP[ls0] = hw; loP[ls0] = lw;                                           \
    }                                                                           \
    if (act1) {                                                                 \
        float d0 = val1 ? (ra_1.x - rb_1.x) * ct : 0.f;                         \
        float d1 = val1 ? (ra_1.y - rb_1.y) * ct : 0.f;                         \
        unsigned hw, lw; pack2(d0, d1, hw, lw);                                 \
        hiP[ls1] = hw; loP[ls1] = lw;                                           \
    }                                                                           \
    unsigned rl_  = rndb(ct);                                                   \
    unsigned achi = rl_ >> 16;                                                  \
    float    cte_ = ct - __uint_as_float(rl_ & 0xffff0000u);                    \
    unsigned aclo = rndb(cte_) >> 16;                                           \
    __syncthreads();                                                            \
    if (t_ + 1 < TS) {                                                          \
        const int s2n = ((t_ + 2) * BB + bz) * (HH * WW);                       \
        rb_0 = ra_0; rb_1 = ra_1;                                               \
        if (val0) ra_0 = xp2[s2n + off0];                                       \
        if (val1) ra_1 = xp2[s2n + off1];                                       \
    }                                                                           \
    unsigned h0=0,h1=0,h2=0,l0=0,l1=0,l2=0;                                     \
    unsigned h3=0,h4=0,h5=0,l3=0,l4=0,l5=0;                                     \
    if (q < 3) {                                                                \
        const unsigned* hp = hiP + q * LROWD + relpx;                           \
        const unsigned* lp = loP + q * LROWD + relpx;                           \
        h0 = hp[0]; h1 = hp[1]; h2 = hp[2];                                     \
        l0 = lp[0]; l1 = lp[1]; l2 = lp[2];                                     \
        h3 = hp[LROWD]; h4 = hp[LROWD + 1]; h5 = hp[LROWD + 2];                 \
        l3 = lp[LROWD]; l4 = lp[LROWD + 1]; l5 = lp[LROWD + 2];                 \
    }                                                                           \
    const bool q3_ = (q == 3);                                                  \
    int4v a0h = {(int)(q3_ ? achi : h0), (int)h1, (int)h2, 0};                  \
    int4v a0l = {(int)(q3_ ? aclo : l0), (int)l1, (int)l2, 0};                  \
    int4v a1h = {(int)(q3_ ? achi : h3), (int)h4, (int)h5, 0};                  \
    int4v a1l = {(int)(q3_ ? aclo : l3), (int)l4, (int)l5, 0};                  \
    short8 A0h = __builtin_bit_cast(short8, a0h);                               \
    short8 A0l = __builtin_bit_cast(short8, a0l);                               \
    short8 A1h = __builtin_bit_cast(short8, a1h);                               \
    short8 A1l = __builtin_bit_cast(short8, a1l);                               \
    int cpack = 0;                                                              \
    _Pragma("unroll")                                                           \
    for (int cg = 0; cg < 4; ++cg) {                                            \
        float4v w0 = W0[cg], w1 = W1[cg];                                       \
        w0 = __builtin_amdgcn_mfma_f32_16x16x32_bf16(A0h, Bh[cg], w0, 0, 0, 0); \
        w1 = __builtin_amdgcn_mfma_f32_16x16x32_bf16(A1h, Bh[cg], w1, 0, 0, 0); \
        w0 = __builtin_amdgcn_mfma_f32_16x16x32_bf16(A0l, Bh[cg], w0, 0, 0, 0); \
        w1 = __builtin_amdgcn_mfma_f32_16x16x32_bf16(A1l, Bh[cg], w1, 0, 0, 0); \
        w0 = __builtin_amdgcn_mfma_f32_16x16x32_bf16(A0h, Bl[cg], w0, 0, 0, 0); \
        w1 = __builtin_amdgcn_mfma_f32_16x16x32_bf16(A1h, Bl[cg], w1, 0, 0, 0); \
        int c = 0;                                                              \
        _Pragma("unroll")                                                       \
        for (int r = 0; r < 4; ++r) {                                           \
            float v0 = w0[r]; bool s0 = v0 > ct; float m0 = v0 - ct;            \
            w0[r] = s0 ? m0 : v0; c += s0;                                      \
            float v1 = w1[r]; bool s1 = v1 > ct; float m1 = v1 - ct;            \
            w1[r] = s1 ? m1 : v1; c += s1;                                      \
        }                                                                       \
        W0[cg] = w0; W1[cg] = w1;                                               \
        cpack |= c << (8 * cg);                                                 \
    }                                                                           \
    cpack += __shfl_xor(cpack, 16);                                             \
    cpack += __shfl_xor(cpack, 32);                                             \
    atomicAdd(spt, (cpack >> qsh) & 255);                                       \
    spt += BB * CHN;                                                            \
    ct *= INVB;                                                                 \
} while (0)

    STEP(0, 0);
#pragma unroll 1
    for (int tt = 1; tt + 1 < TS; tt += 2) {     // covers t = 1..18 (TS-1 even pairs)
        STEP(tt, 1);
        STEP(tt + 1, 0);
    }
#undef STEP
}

// ---------------------------------------------------------------------------
// head: one block per batch b. Computes logits[t][b][:] directly, readout[b][:]
// locally (no atomics), and one atomicAdd per block into the sr scalar
// (zeroed by lif_main). No d_out memset needed.
// ---------------------------------------------------------------------------
__global__ __launch_bounds__(256) void head_kernel(const int* __restrict__ spikesum,
                                                   const float* __restrict__ w_head,
                                                   const float* __restrict__ b_head,
                                                   float* __restrict__ out) {
    const int b    = blockIdx.x;
    const int lane = threadIdx.x & 63;
    const int wv   = threadIdx.x >> 6;           // 0..3, wave handles t = wv, wv+4, ...
    __shared__ float red[4][NOUT + 1];

    float wrow[NOUT];
#pragma unroll
    for (int o = 0; o < NOUT; ++o) wrow[o] = w_head[lane * NOUT + o] * (1.f / (HH * WW));

    float racc[NOUT];
#pragma unroll
    for (int o = 0; o < NOUT; ++o) racc[o] = 0.f;
    float ftot = 0.f;

    for (int t = wv; t < TS; t += 4) {
        float s = (float)spikesum[(t * BB + b) * CHN + lane];
        float acc[NOUT];
#pragma unroll
        for (int o = 0; o < NOUT; ++o) acc[o] = s * wrow[o];
        float tt = s;
#pragma unroll
        for (int off = 32; off > 0; off >>= 1) {
#pragma unroll
            for (int o = 0; o < NOUT; ++o) acc[o] += __shfl_down(acc[o], off);
            tt += __shfl_down(tt, off);
        }
        if (lane == 0) {
#pragma unroll
            for (int o = 0; o < NOUT; ++o) {
                float lg = acc[o] + b_head[o];
                out[BB * NOUT + (t * BB + b) * NOUT + o] = lg;
                racc[o] += lg;
            }
            ftot += tt;
        }
    }
    if (lane == 0) {
#pragma unroll
        for (int o = 0; o < NOUT; ++o) red[wv][o] = racc[o];
        red[wv][NOUT] = ftot;
    }
    __syncthreads();
    if (threadIdx.x < NOUT) {
        float r = red[0][threadIdx.x] + red[1][threadIdx.x] +
                  red[2][threadIdx.x] + red[3][threadIdx.x];
        out[b * NOUT + threadIdx.x] = r * (1.f / TS);
    } else if (threadIdx.x == NOUT) {
        float ft = red[0][NOUT] + red[1][NOUT] + red[2][NOUT] + red[3][NOUT];
        atomicAdd(&out[SR_IDX], ft * (1.f / ((float)TS * BB * HH * WW * CHN)));
    }
}

// ---------------------------------------------------------------------------
extern "C" void kernel_launch(void* const* d_in, const int* in_sizes, int n_in,
                              void* d_out, int out_size, void* d_ws, size_t ws_size,
                              hipStream_t stream) {
    (void)in_sizes; (void)n_in; (void)ws_size; (void)out_size;
    const float* x      = (const float*)d_in[0];
    const float* w_conv = (const float*)d_in[1];
    const float* b_conv = (const float*)d_in[2];
    const float* w_head = (const float*)d_in[3];
    const float* b_head = (const float*)d_in[4];
    float* out      = (float*)d_out;
    int*   spikesum = (int*)d_ws;

    (void)hipMemsetAsync(d_ws, 0, SPIKESUM_BYTES, stream);

    lif_main<<<dim3(2, HH / 2, BB), 256, 0, stream>>>(x, w_conv, b_conv, spikesum, out);
    head_kernel<<<dim3(BB), 256, 0, stream>>>(spikesum, w_head, b_head, out);
}

// Round 2
// 195.143 us; speedup vs baseline: 1.0587x; 1.0246x over previous
//
#include <hip/hip_runtime.h>
#include <hip/hip_bf16.h>

// Problem constants
#define TT   20
#define TS   19          // T-1 steps
#define BB   16
#define HH   128
#define WW   128
#define CINN 2
#define CHN  64
#define NOUT 10
#define BETA 0.9f
#define INVB (1.0f / BETA)
#define THRV 1.0f

#define SPIKESUM_ELEMS (TS*BB*CHN)           // 19,456 ints
#define SPIKESUM_BYTES (SPIKESUM_ELEMS*4)    // 77,824 B
#define SR_IDX (BB*NOUT + TS*BB*NOUT)        // scalar spike-rate slot in out

#define LROW  20                              // dwords per staged row (18 + 2 pad)

typedef __attribute__((ext_vector_type(8))) short short8;
typedef __attribute__((ext_vector_type(4))) float float4v;
typedef __attribute__((ext_vector_type(4))) int   int4v;

// round-to-nearest-even fp32 -> bf16 bits
__device__ __forceinline__ unsigned rne16(float f) {
    unsigned u = __float_as_uint(f);
    return (u + 0x7fffu + ((u >> 16) & 1u)) >> 16;
}
__device__ __forceinline__ float b2f(unsigned us) { return __uint_as_float(us << 16); }
__device__ __forceinline__ unsigned rndb(float f) {          // rounded bits, un-shifted
    unsigned u = __float_as_uint(f);
    return u + 0x7fffu + ((u >> 16) & 1u);
}
// hi/lo bf16 split of a pixel-pair, packed via v_perm.
__device__ __forceinline__ void pack2(float d0, float d1, unsigned &hi, unsigned &lo) {
    unsigned r0 = rndb(d0), r1 = rndb(d1);
    hi = __builtin_amdgcn_perm(r1, r0, 0x07060302u);
    float e0 = d0 - __uint_as_float(r0 & 0xffff0000u);
    float e1 = d1 - __uint_as_float(r1 & 0xffff0000u);
    lo = __builtin_amdgcn_perm(rndb(e1), rndb(e0), 0x07060302u);
}

// ---------------------------------------------------------------------------
// Fused flow-diff + 3x3 conv (bf16-split MFMA) + W-space LIF + spike count.
//
// BARRIER-FREE: each wave owns a private 16-px x 2-row output tile and stages
// its own 4-row x 18-pair halo into a private LDS region (double-buffered).
// No __syncthreads anywhere — all LDS deps are same-wave lgkmcnt waits, so
// resident waves drift freely and hide each other's latency.
//
// W-space LIF (W_t = V_t / beta^t): W += conv_t * beta^-t via the MFMA
// C-operand; spike iff W > thr_cg = ct - b_ch*S_t (bias folded into the
// threshold: S_t = sum_{tau<=t} beta^-tau), reset W -= ct.  This removes the
// bias tap, the per-t ct hi/lo split, and all A-fragment cndmasks
// (A elem3 is constant 0).
// ---------------------------------------------------------------------------
__global__ __launch_bounds__(256, 4) void lif_main(const float* __restrict__ x,
                                                   const float* __restrict__ w_conv,
                                                   const float* __restrict__ b_conv,
                                                   int* __restrict__ spikesum,
                                                   float* __restrict__ out) {
    __shared__ unsigned lds[4][2][2][4 * LROW];  // [wave][buf][plane][row*20+dx] = 5120 B

    const float2* xp2 = (const float2*)x;        // pixel-granular (ci pair)
    const int FRAME2  = BB * HH * WW;            // float2s per time slice

    const int tid  = threadIdx.x;
    const int lane = tid & 63;
    const int wv   = __builtin_amdgcn_readfirstlane(tid >> 6); // uniform 0..3
    const int bx   = blockIdx.x;                 // 0..1 : pixel half
    const int r0   = blockIdx.y << 1;            // first of 2 output rows
    const int bz   = blockIdx.z;                 // batch
    const int q    = lane >> 4;                  // quad
    const int col  = lane & 15;
    const int x0   = (bx << 6) + (wv << 4);      // wave's 16-px slice base

    // zero the cross-block-accumulated sr scalar (head adds later in-stream)
    if (bx == 0 && blockIdx.y == 0 && bz == 0 && tid == 0) out[SR_IDX] = 0.f;

    // ---- per-wave staging slots (pair = one pixel, both ci); 72 pairs/wave
    // slot0: pair = lane (0..63) ; slot1: pair = 64+lane (lane<8 -> row3, dx 10+lane)
    const int  row0 = lane / 18, dx0 = lane - row0 * 18;
    const int  y0s  = r0 - 1 + row0;
    const int  px0s = x0 - 1 + dx0;
    const bool val0 = ((unsigned)y0s < (unsigned)HH) && ((unsigned)px0s < (unsigned)WW);
    const int  off0 = val0 ? (y0s * WW + px0s) : 0;
    const int  ls0  = row0 * LROW + dx0;

    const bool act1 = (lane < 8);
    const int  y1s  = r0 + 2;
    const int  px1s = x0 - 1 + 10 + lane;
    const bool val1 = act1 && ((unsigned)y1s < (unsigned)HH) && ((unsigned)px1s < (unsigned)WW);
    const int  off1 = val1 ? (y1s * WW + px1s) : 0;
    const int  ls1  = 3 * LROW + 10 + lane;

    // ---- B fragments: k = q*8+j ; q<3: 6 weight taps ; q==3: all zero
    short8 Bh[4], Bl[4];
#pragma unroll
    for (int cg = 0; cg < 4; ++cg) {
        int hi_i[4] = {0, 0, 0, 0}, lo_i[4] = {0, 0, 0, 0};
        if (q < 3) {
#pragma unroll
            for (int j = 0; j < 6; ++j) {
                float w = w_conv[((q * 3 + (j >> 1)) * 2 + (j & 1)) * CHN + cg * 16 + col];
                unsigned hs = rne16(w);
                unsigned ls = rne16(w - b2f(hs));
                hi_i[j >> 1] |= (int)(hs << (16 * (j & 1)));
                lo_i[j >> 1] |= (int)(ls << (16 * (j & 1)));
            }
        }
        int4v hv = {hi_i[0], hi_i[1], hi_i[2], hi_i[3]};
        int4v lv = {lo_i[0], lo_i[1], lo_i[2], lo_i[3]};
        Bh[cg] = __builtin_bit_cast(short8, hv);
        Bl[cg] = __builtin_bit_cast(short8, lv);
    }

    // bias (negated) per cg for the threshold fold (b_conv may be nonzero)
    float nb[4];
#pragma unroll
    for (int cg = 0; cg < 4; ++cg) nb[cg] = -b_conv[cg * 16 + col];

    float4v W0[4], W1[4];                        // membrane (W-space), rows r0, r0+1
#pragma unroll
    for (int cg = 0; cg < 4; ++cg) {
        W0[cg] = (float4v){0.f, 0.f, 0.f, 0.f};
        W1[cg] = (float4v){0.f, 0.f, 0.f, 0.f};
    }

    float ct = 1.0f;                             // beta^-t
    float S  = 1.0f;                             // sum_{tau<=t} beta^-tau
    int* spt = spikesum + bz * CHN + lane;

    // ---- preheader: rb = x[0], ra = x[1]
    float2 ra_0 = {0.f, 0.f}, rb_0 = {0.f, 0.f};
    float2 ra_1 = {0.f, 0.f}, rb_1 = {0.f, 0.f};
    const float2* xb = xp2 + bz * HH * WW;
    if (val0) { rb_0 = xb[off0]; ra_0 = xb[FRAME2 + off0]; }
    if (val1) { rb_1 = xb[off1]; ra_1 = xb[FRAME2 + off1]; }
    const float2* xn = xb + 2 * FRAME2;          // prefetch cursor: slice t+2

#define STEP(T_, BSEL) do {                                                     \
    unsigned* hiP = &lds[wv][BSEL][0][0];                                       \
    unsigned* loP = &lds[wv][BSEL][1][0];                                       \
    {                                                                           \
        float d0 = (ra_0.x - rb_0.x) * ct;                                      \
        float d1 = (ra_0.y - rb_0.y) * ct;                                      \
        unsigned hw, lw; pack2(d0, d1, hw, lw);                                 \
        hiP[ls0] = hw; loP[ls0] = lw;                                           \
    }                                                                           \
    if (act1) {                                                                 \
        float d0 = (ra_1.x - rb_1.x) * ct;                                      \
        float d1 = (ra_1.y - rb_1.y) * ct;                                      \
        unsigned hw, lw; pack2(d0, d1, hw, lw);                                 \
        hiP[ls1] = hw; loP[ls1] = lw;                                           \
    }                                                                           \
    if ((T_) + 1 < TS) {                                                        \
        rb_0 = ra_0; rb_1 = ra_1;                                               \
        if (val0) ra_0 = xn[off0];                                              \
        if (val1) ra_1 = xn[off1];                                              \
        xn += FRAME2;                                                           \
    }                                                                           \
    unsigned h0=0,h1=0,h2=0,l0=0,l1=0,l2=0;                                     \
    unsigned h3=0,h4=0,h5=0,l3=0,l4=0,l5=0;                                     \
    if (q < 3) {                                                                \
        const unsigned* hp = hiP + q * LROW + col;                              \
        const unsigned* lp = loP + q * LROW + col;                              \
        h0 = hp[0]; h1 = hp[1]; h2 = hp[2];                                     \
        l0 = lp[0]; l1 = lp[1]; l2 = lp[2];                                     \
        h3 = hp[LROW]; h4 = hp[LROW + 1]; h5 = hp[LROW + 2];                    \
        l3 = lp[LROW]; l4 = lp[LROW + 1]; l5 = lp[LROW + 2];                    \
    }                                                                           \
    int4v a0h = {(int)h0, (int)h1, (int)h2, 0};                                 \
    int4v a0l = {(int)l0, (int)l1, (int)l2, 0};                                 \
    int4v a1h = {(int)h3, (int)h4, (int)h5, 0};                                 \
    int4v a1l = {(int)l3, (int)l4, (int)l5, 0};                                 \
    short8 A0h = __builtin_bit_cast(short8, a0h);                               \
    short8 A0l = __builtin_bit_cast(short8, a0l);                               \
    short8 A1h = __builtin_bit_cast(short8, a1h);                               \
    short8 A1l = __builtin_bit_cast(short8, a1l);                               \
    int cpack = 0;                                                              \
    _Pragma("unroll")                                                           \
    for (int cg = 0; cg < 4; ++cg) {                                            \
        float thr = fmaf(nb[cg], S, ct);                                        \
        float4v w0 = W0[cg], w1 = W1[cg];                                       \
        w0 = __builtin_amdgcn_mfma_f32_16x16x32_bf16(A0h, Bh[cg], w0, 0, 0, 0); \
        w1 = __builtin_amdgcn_mfma_f32_16x16x32_bf16(A1h, Bh[cg], w1, 0, 0, 0); \
        w0 = __builtin_amdgcn_mfma_f32_16x16x32_bf16(A0l, Bh[cg], w0, 0, 0, 0); \
        w1 = __builtin_amdgcn_mfma_f32_16x16x32_bf16(A1l, Bh[cg], w1, 0, 0, 0); \
        w0 = __builtin_amdgcn_mfma_f32_16x16x32_bf16(A0h, Bl[cg], w0, 0, 0, 0); \
        w1 = __builtin_amdgcn_mfma_f32_16x16x32_bf16(A1h, Bl[cg], w1, 0, 0, 0); \
        int c = 0;                                                              \
        _Pragma("unroll")                                                       \
        for (int r = 0; r < 4; ++r) {                                           \
            float v0 = w0[r]; bool s0 = v0 > thr;                               \
            w0[r] = s0 ? (v0 - ct) : v0; c += s0;                               \
            float v1 = w1[r]; bool s1 = v1 > thr;                               \
            w1[r] = s1 ? (v1 - ct) : v1; c += s1;                               \
        }                                                                       \
        W0[cg] = w0; W1[cg] = w1;                                               \
        cpack |= c << (8 * cg);                                                 \
    }                                                                           \
    cpack += __shfl_xor(cpack, 16);                                             \
    cpack += __shfl_xor(cpack, 32);                                             \
    atomicAdd(spt, (cpack >> (q << 3)) & 255);                                  \
    spt += BB * CHN;                                                            \
    ct *= INVB; S += ct;                                                        \
} while (0)

    STEP(0, 0);
#pragma unroll 1
    for (int t = 1; t + 1 < TS; t += 2) {        // covers t = 1..18
        STEP(t, 1);
        STEP(t + 1, 0);
    }
#undef STEP
}

// ---------------------------------------------------------------------------
// head: one block per batch b. Computes logits[t][b][:] directly, readout[b][:]
// locally (no atomics), and one atomicAdd per block into the sr scalar
// (zeroed by lif_main). No d_out memset needed.
// ---------------------------------------------------------------------------
__global__ __launch_bounds__(256) void head_kernel(const int* __restrict__ spikesum,
                                                   const float* __restrict__ w_head,
                                                   const float* __restrict__ b_head,
                                                   float* __restrict__ out) {
    const int b    = blockIdx.x;
    const int lane = threadIdx.x & 63;
    const int wv   = threadIdx.x >> 6;           // 0..3, wave handles t = wv, wv+4, ...
    __shared__ float red[4][NOUT + 1];

    float wrow[NOUT];
#pragma unroll
    for (int o = 0; o < NOUT; ++o) wrow[o] = w_head[lane * NOUT + o] * (1.f / (HH * WW));

    float racc[NOUT];
#pragma unroll
    for (int o = 0; o < NOUT; ++o) racc[o] = 0.f;
    float ftot = 0.f;

    for (int t = wv; t < TS; t += 4) {
        float s = (float)spikesum[(t * BB + b) * CHN + lane];
        float acc[NOUT];
#pragma unroll
        for (int o = 0; o < NOUT; ++o) acc[o] = s * wrow[o];
        float tt = s;
#pragma unroll
        for (int off = 32; off > 0; off >>= 1) {
#pragma unroll
            for (int o = 0; o < NOUT; ++o) acc[o] += __shfl_down(acc[o], off);
            tt += __shfl_down(tt, off);
        }
        if (lane == 0) {
#pragma unroll
            for (int o = 0; o < NOUT; ++o) {
                float lg = acc[o] + b_head[o];
                out[BB * NOUT + (t * BB + b) * NOUT + o] = lg;
                racc[o] += lg;
            }
            ftot += tt;
        }
    }
    if (lane == 0) {
#pragma unroll
        for (int o = 0; o < NOUT; ++o) red[wv][o] = racc[o];
        red[wv][NOUT] = ftot;
    }
    __syncthreads();
    if (threadIdx.x < NOUT) {
        float r = red[0][threadIdx.x] + red[1][threadIdx.x] +
                  red[2][threadIdx.x] + red[3][threadIdx.x];
        out[b * NOUT + threadIdx.x] = r * (1.f / TS);
    } else if (threadIdx.x == NOUT) {
        float ft = red[0][NOUT] + red[1][NOUT] + red[2][NOUT] + red[3][NOUT];
        atomicAdd(&out[SR_IDX], ft * (1.f / ((float)TS * BB * HH * WW * CHN)));
    }
}

// ---------------------------------------------------------------------------
extern "C" void kernel_launch(void* const* d_in, const int* in_sizes, int n_in,
                              void* d_out, int out_size, void* d_ws, size_t ws_size,
                              hipStream_t stream) {
    (void)in_sizes; (void)n_in; (void)ws_size; (void)out_size;
    const float* x      = (const float*)d_in[0];
    const float* w_conv = (const float*)d_in[1];
    const float* b_conv = (const float*)d_in[2];
    const float* w_head = (const float*)d_in[3];
    const float* b_head = (const float*)d_in[4];
    float* out      = (float*)d_out;
    int*   spikesum = (int*)d_ws;

    (void)hipMemsetAsync(d_ws, 0, SPIKESUM_BYTES, stream);

    lif_main<<<dim3(2, HH / 2, BB), 256, 0, stream>>>(x, w_conv, b_conv, spikesum, out);
    head_kernel<<<dim3(BB), 256, 0, stream>>>(spikesum, w_head, b_head, out);
}

// Round 3
// 194.861 us; speedup vs baseline: 1.0602x; 1.0015x over previous
//
#include <hip/hip_runtime.h>
#include <hip/hip_bf16.h>

// Problem constants
#define TT   20
#define TS   19          // T-1 steps
#define BB   16
#define HH   128
#define WW   128
#define CINN 2
#define CHN  64
#define NOUT 10
#define BETA 0.9f
#define INVB (1.0f / BETA)
#define THRV 1.0f

#define SPIKESUM_ELEMS (TS*BB*CHN)           // 19,456 ints
#define SPIKESUM_BYTES (SPIKESUM_ELEMS*4)    // 77,824 B
#define SR_IDX (BB*NOUT + TS*BB*NOUT)        // scalar spike-rate slot in out

#define LROW  20                              // dwords per staged row (18 + 2 pad)

typedef __attribute__((ext_vector_type(8))) short short8;
typedef __attribute__((ext_vector_type(4))) float float4v;
typedef __attribute__((ext_vector_type(4))) int   int4v;

// round-to-nearest-even fp32 -> bf16 bits
__device__ __forceinline__ unsigned rne16(float f) {
    unsigned u = __float_as_uint(f);
    return (u + 0x7fffu + ((u >> 16) & 1u)) >> 16;
}
__device__ __forceinline__ float b2f(unsigned us) { return __uint_as_float(us << 16); }
__device__ __forceinline__ unsigned rndb(float f) {          // rounded bits, un-shifted
    unsigned u = __float_as_uint(f);
    return u + 0x7fffu + ((u >> 16) & 1u);
}
// hi/lo bf16 split of a pixel-pair, packed via v_perm.
__device__ __forceinline__ void pack2(float d0, float d1, unsigned &hi, unsigned &lo) {
    unsigned r0 = rndb(d0), r1 = rndb(d1);
    hi = __builtin_amdgcn_perm(r1, r0, 0x07060302u);
    float e0 = d0 - __uint_as_float(r0 & 0xffff0000u);
    float e1 = d1 - __uint_as_float(r1 & 0xffff0000u);
    lo = __builtin_amdgcn_perm(rndb(e1), rndb(e0), 0x07060302u);
}

// ---------------------------------------------------------------------------
// Fused flow-diff + 3x3 conv (bf16-split MFMA) + W-space LIF + spike count.
//
// Barrier-free per-wave tiles (16px x 2 rows), PIPELINED one step ahead:
// iter t reads A-fragments staged at iter t-1 (full-iteration producer-
// consumer distance, no same-buffer write->read stall), then stages t+1.
// MFMA issue is product-type-outer (8 independent accumulate chains between
// dependent issues -> no MFMA latency stalls). q==3 lanes read row0 data
// unguarded (B(q3)=0 nullifies; staged bf16 always finite) -> no per-iter
// zero-reinit movs, loads land directly in operand quads.
//
// W-space LIF (W_t = V_t / beta^t): W += conv_t * beta^-t via the MFMA
// C-operand; spike iff W > thr = ct - b_ch*S_t, reset W -= ct.
// ---------------------------------------------------------------------------
__global__ __launch_bounds__(256, 4) void lif_main(const float* __restrict__ x,
                                                   const float* __restrict__ w_conv,
                                                   const float* __restrict__ b_conv,
                                                   int* __restrict__ spikesum,
                                                   float* __restrict__ out) {
    __shared__ unsigned lds[4][2][2][4 * LROW];  // [wave][buf][plane][row*20+dx] = 5120 B

    const float2* xp2 = (const float2*)x;        // pixel-granular (ci pair)
    const int FRAME2  = BB * HH * WW;            // float2s per time slice

    const int tid  = threadIdx.x;
    const int lane = tid & 63;
    const int wv   = __builtin_amdgcn_readfirstlane(tid >> 6); // uniform 0..3
    const int bx   = blockIdx.x;                 // 0..1 : pixel half
    const int r0   = blockIdx.y << 1;            // first of 2 output rows
    const int bz   = blockIdx.z;                 // batch
    const int q    = lane >> 4;                  // quad
    const int col  = lane & 15;
    const int x0   = (bx << 6) + (wv << 4);      // wave's 16-px slice base

    // zero the cross-block-accumulated sr scalar (head adds later in-stream)
    if (bx == 0 && blockIdx.y == 0 && bz == 0 && tid == 0) out[SR_IDX] = 0.f;

    // ---- per-wave staging slots (pair = one pixel, both ci); 72 pairs/wave
    const int  row0 = lane / 18, dx0 = lane - row0 * 18;
    const int  y0s  = r0 - 1 + row0;
    const int  px0s = x0 - 1 + dx0;
    const bool val0 = ((unsigned)y0s < (unsigned)HH) && ((unsigned)px0s < (unsigned)WW);
    const int  off0 = val0 ? (y0s * WW + px0s) : 0;
    const int  ls0  = row0 * LROW + dx0;

    const bool act1 = (lane < 8);
    const int  y1s  = r0 + 2;
    const int  px1s = x0 - 1 + 10 + lane;
    const bool val1 = act1 && ((unsigned)y1s < (unsigned)HH) && ((unsigned)px1s < (unsigned)WW);
    const int  off1 = val1 ? (y1s * WW + px1s) : 0;
    const int  ls1  = 3 * LROW + 10 + lane;

    // A-read base: q==3 reads row0 (finite garbage x B==0 -> exact 0)
    const int rq  = (q < 3) ? q : 0;
    const int rdb = rq * LROW + col;

    // ---- B fragments: k = q*8+j ; q<3: 6 weight taps ; q==3: all zero
    short8 Bh[4], Bl[4];
#pragma unroll
    for (int cg = 0; cg < 4; ++cg) {
        int hi_i[4] = {0, 0, 0, 0}, lo_i[4] = {0, 0, 0, 0};
        if (q < 3) {
#pragma unroll
            for (int j = 0; j < 6; ++j) {
                float w = w_conv[((q * 3 + (j >> 1)) * 2 + (j & 1)) * CHN + cg * 16 + col];
                unsigned hs = rne16(w);
                unsigned ls = rne16(w - b2f(hs));
                hi_i[j >> 1] |= (int)(hs << (16 * (j & 1)));
                lo_i[j >> 1] |= (int)(ls << (16 * (j & 1)));
            }
        }
        int4v hv = {hi_i[0], hi_i[1], hi_i[2], hi_i[3]};
        int4v lv = {lo_i[0], lo_i[1], lo_i[2], lo_i[3]};
        Bh[cg] = __builtin_bit_cast(short8, hv);
        Bl[cg] = __builtin_bit_cast(short8, lv);
    }

    // bias (negated) per cg for the threshold fold
    float nb[4];
#pragma unroll
    for (int cg = 0; cg < 4; ++cg) nb[cg] = -b_conv[cg * 16 + col];

    float4v W0[4], W1[4];                        // membrane (W-space), rows r0, r0+1
#pragma unroll
    for (int cg = 0; cg < 4; ++cg) {
        W0[cg] = (float4v){0.f, 0.f, 0.f, 0.f};
        W1[cg] = (float4v){0.f, 0.f, 0.f, 0.f};
    }

    float ct = 1.0f;                             // beta^-t
    float S  = 1.0f;                             // sum_{tau<=t} beta^-tau
    int* spt = spikesum + bz * CHN + lane;

    // ---- preheader: rb = x[0], ra = x[1]; stage t=0 into buf0; advance
    float2 ra_0 = {0.f, 0.f}, rb_0 = {0.f, 0.f};
    float2 ra_1 = {0.f, 0.f}, rb_1 = {0.f, 0.f};
    const float2* xb = xp2 + bz * HH * WW;
    if (val0) { rb_0 = xb[off0]; ra_0 = xb[FRAME2 + off0]; }
    if (val1) { rb_1 = xb[off1]; ra_1 = xb[FRAME2 + off1]; }
    {
        unsigned* hiW = &lds[wv][0][0][0];
        unsigned* loW = &lds[wv][0][1][0];
        {
            float d0 = (ra_0.x - rb_0.x), d1 = (ra_0.y - rb_0.y);
            unsigned hw, lw; pack2(d0, d1, hw, lw);
            hiW[ls0] = hw; loW[ls0] = lw;
        }
        if (act1) {
            float d0 = (ra_1.x - rb_1.x), d1 = (ra_1.y - rb_1.y);
            unsigned hw, lw; pack2(d0, d1, hw, lw);
            hiW[ls1] = hw; loW[ls1] = lw;
        }
        rb_0 = ra_0; rb_1 = ra_1;
        if (val0) ra_0 = xb[2 * FRAME2 + off0];
        if (val1) ra_1 = xb[2 * FRAME2 + off1];
    }
    const float2* xn = xb + 3 * FRAME2;          // prefetch cursor: slice t+3

#define STEP(T_, CUR, NXT) do {                                                 \
    /* 1. A-fragment reads (data staged one iteration ago) */                   \
    const unsigned* hiR = &lds[wv][CUR][0][0] + rdb;                            \
    const unsigned* loR = &lds[wv][CUR][1][0] + rdb;                            \
    unsigned h0 = hiR[0], h1 = hiR[1], h2 = hiR[2];                             \
    unsigned h3 = hiR[LROW], h4 = hiR[LROW + 1], h5 = hiR[LROW + 2];            \
    unsigned l0 = loR[0], l1 = loR[1], l2 = loR[2];                             \
    unsigned l3 = loR[LROW], l4 = loR[LROW + 1], l5 = loR[LROW + 2];            \
    /* 2. stage t+1 into the other buffer (overlaps read latency) */            \
    float ctn = ct * INVB;                                                      \
    if ((T_) + 1 < TS) {                                                        \
        unsigned* hiW = &lds[wv][NXT][0][0];                                    \
        unsigned* loW = &lds[wv][NXT][1][0];                                    \
        {                                                                       \
            float d0 = (ra_0.x - rb_0.x) * ctn;                                 \
            float d1 = (ra_0.y - rb_0.y) * ctn;                                 \
            unsigned hw, lw; pack2(d0, d1, hw, lw);                             \
            hiW[ls0] = hw; loW[ls0] = lw;                                       \
        }                                                                       \
        if (act1) {                                                             \
            float d0 = (ra_1.x - rb_1.x) * ctn;                                 \
            float d1 = (ra_1.y - rb_1.y) * ctn;                                 \
            unsigned hw, lw; pack2(d0, d1, hw, lw);                             \
            hiW[ls1] = hw; loW[ls1] = lw;                                       \
        }                                                                       \
        rb_0 = ra_0; rb_1 = ra_1;                                               \
        if ((T_) + 3 < TT) {                                                    \
            if (val0) ra_0 = xn[off0];                                          \
            if (val1) ra_1 = xn[off1];                                          \
            xn += FRAME2;                                                       \
        }                                                                       \
    }                                                                           \
    /* 3. assemble A, 3-pass MFMA (8 independent chains per pass), LIF */       \
    int4v a0h = {(int)h0, (int)h1, (int)h2, 0};                                 \
    int4v a0l = {(int)l0, (int)l1, (int)l2, 0};                                 \
    int4v a1h = {(int)h3, (int)h4, (int)h5, 0};                                 \
    int4v a1l = {(int)l3, (int)l4, (int)l5, 0};                                 \
    short8 A0h = __builtin_bit_cast(short8, a0h);                               \
    short8 A0l = __builtin_bit_cast(short8, a0l);                               \
    short8 A1h = __builtin_bit_cast(short8, a1h);                               \
    short8 A1l = __builtin_bit_cast(short8, a1l);                               \
    _Pragma("unroll")                                                           \
    for (int cg = 0; cg < 4; ++cg) {                                            \
        W0[cg] = __builtin_amdgcn_mfma_f32_16x16x32_bf16(A0h, Bh[cg], W0[cg], 0, 0, 0); \
        W1[cg] = __builtin_amdgcn_mfma_f32_16x16x32_bf16(A1h, Bh[cg], W1[cg], 0, 0, 0); \
    }                                                                           \
    _Pragma("unroll")                                                           \
    for (int cg = 0; cg < 4; ++cg) {                                            \
        W0[cg] = __builtin_amdgcn_mfma_f32_16x16x32_bf16(A0l, Bh[cg], W0[cg], 0, 0, 0); \
        W1[cg] = __builtin_amdgcn_mfma_f32_16x16x32_bf16(A1l, Bh[cg], W1[cg], 0, 0, 0); \
    }                                                                           \
    _Pragma("unroll")                                                           \
    for (int cg = 0; cg < 4; ++cg) {                                            \
        W0[cg] = __builtin_amdgcn_mfma_f32_16x16x32_bf16(A0h, Bl[cg], W0[cg], 0, 0, 0); \
        W1[cg] = __builtin_amdgcn_mfma_f32_16x16x32_bf16(A1h, Bl[cg], W1[cg], 0, 0, 0); \
    }                                                                           \
    int cpack = 0;                                                              \
    _Pragma("unroll")                                                           \
    for (int cg = 0; cg < 4; ++cg) {                                            \
        float thr = fmaf(nb[cg], S, ct);                                        \
        float4v w0 = W0[cg], w1 = W1[cg];                                       \
        int c = 0;                                                              \
        _Pragma("unroll")                                                       \
        for (int r = 0; r < 4; ++r) {                                           \
            float v0 = w0[r]; bool s0 = v0 > thr;                               \
            w0[r] = s0 ? (v0 - ct) : v0; c += s0;                               \
            float v1 = w1[r]; bool s1 = v1 > thr;                               \
            w1[r] = s1 ? (v1 - ct) : v1; c += s1;                               \
        }                                                                       \
        W0[cg] = w0; W1[cg] = w1;                                               \
        cpack |= c << (8 * cg);                                                 \
    }                                                                           \
    cpack += __shfl_xor(cpack, 16);                                             \
    cpack += __shfl_xor(cpack, 32);                                             \
    atomicAdd(spt, (cpack >> (q << 3)) & 255);                                  \
    spt += BB * CHN;                                                            \
    ct = ctn; S += ctn;                                                         \
} while (0)

    STEP(0, 0, 1);
#pragma unroll 1
    for (int t = 1; t + 1 < TS; t += 2) {        // covers t = 1..18
        STEP(t, 1, 0);
        STEP(t + 1, 0, 1);
    }
#undef STEP
}

// ---------------------------------------------------------------------------
// head: one block per batch b. Computes logits[t][b][:] directly, readout[b][:]
// locally (no atomics), and one atomicAdd per block into the sr scalar
// (zeroed by lif_main). No d_out memset needed.
// ---------------------------------------------------------------------------
__global__ __launch_bounds__(256) void head_kernel(const int* __restrict__ spikesum,
                                                   const float* __restrict__ w_head,
                                                   const float* __restrict__ b_head,
                                                   float* __restrict__ out) {
    const int b    = blockIdx.x;
    const int lane = threadIdx.x & 63;
    const int wv   = threadIdx.x >> 6;           // 0..3, wave handles t = wv, wv+4, ...
    __shared__ float red[4][NOUT + 1];

    float wrow[NOUT];
#pragma unroll
    for (int o = 0; o < NOUT; ++o) wrow[o] = w_head[lane * NOUT + o] * (1.f / (HH * WW));

    float racc[NOUT];
#pragma unroll
    for (int o = 0; o < NOUT; ++o) racc[o] = 0.f;
    float ftot = 0.f;

    for (int t = wv; t < TS; t += 4) {
        float s = (float)spikesum[(t * BB + b) * CHN + lane];
        float acc[NOUT];
#pragma unroll
        for (int o = 0; o < NOUT; ++o) acc[o] = s * wrow[o];
        float tt = s;
#pragma unroll
        for (int off = 32; off > 0; off >>= 1) {
#pragma unroll
            for (int o = 0; o < NOUT; ++o) acc[o] += __shfl_down(acc[o], off);
            tt += __shfl_down(tt, off);
        }
        if (lane == 0) {
#pragma unroll
            for (int o = 0; o < NOUT; ++o) {
                float lg = acc[o] + b_head[o];
                out[BB * NOUT + (t * BB + b) * NOUT + o] = lg;
                racc[o] += lg;
            }
            ftot += tt;
        }
    }
    if (lane == 0) {
#pragma unroll
        for (int o = 0; o < NOUT; ++o) red[wv][o] = racc[o];
        red[wv][NOUT] = ftot;
    }
    __syncthreads();
    if (threadIdx.x < NOUT) {
        float r = red[0][threadIdx.x] + red[1][threadIdx.x] +
                  red[2][threadIdx.x] + red[3][threadIdx.x];
        out[b * NOUT + threadIdx.x] = r * (1.f / TS);
    } else if (threadIdx.x == NOUT) {
        float ft = red[0][NOUT] + red[1][NOUT] + red[2][NOUT] + red[3][NOUT];
        atomicAdd(&out[SR_IDX], ft * (1.f / ((float)TS * BB * HH * WW * CHN)));
    }
}

// ---------------------------------------------------------------------------
extern "C" void kernel_launch(void* const* d_in, const int* in_sizes, int n_in,
                              void* d_out, int out_size, void* d_ws, size_t ws_size,
                              hipStream_t stream) {
    (void)in_sizes; (void)n_in; (void)ws_size; (void)out_size;
    const float* x      = (const float*)d_in[0];
    const float* w_conv = (const float*)d_in[1];
    const float* b_conv = (const float*)d_in[2];
    const float* w_head = (const float*)d_in[3];
    const float* b_head = (const float*)d_in[4];
    float* out      = (float*)d_out;
    int*   spikesum = (int*)d_ws;

    (void)hipMemsetAsync(d_ws, 0, SPIKESUM_BYTES, stream);

    lif_main<<<dim3(2, HH / 2, BB), 256, 0, stream>>>(x, w_conv, b_conv, spikesum, out);
    head_kernel<<<dim3(BB), 256, 0, stream>>>(spikesum, w_head, b_head, out);
}

// Round 4
// 190.224 us; speedup vs baseline: 1.0861x; 1.0244x over previous
//
#include <hip/hip_runtime.h>
#include <hip/hip_bf16.h>

// Problem constants
#define TT   20
#define TS   19          // T-1 steps
#define BB   16
#define HH   128
#define WW   128
#define CINN 2
#define CHN  64
#define NOUT 10
#define BETA 0.9f
#define INVB (1.0f / BETA)
#define THRV 1.0f

#define SPIKESUM_ELEMS (TS*BB*CHN)           // 19,456 ints
#define SPIKESUM_BYTES (SPIKESUM_ELEMS*4)    // 77,824 B
#define SR_IDX (BB*NOUT + TS*BB*NOUT)        // scalar spike-rate slot in out

#define LROW  20                              // dwords per staged row (18 + 2 pad)

typedef __attribute__((ext_vector_type(8))) short short8;
typedef __attribute__((ext_vector_type(4))) float float4v;
typedef __attribute__((ext_vector_type(4))) int   int4v;

// round-to-nearest-even fp32 -> bf16 bits
__device__ __forceinline__ unsigned rne16(float f) {
    unsigned u = __float_as_uint(f);
    return (u + 0x7fffu + ((u >> 16) & 1u)) >> 16;
}
__device__ __forceinline__ float b2f(unsigned us) { return __uint_as_float(us << 16); }
__device__ __forceinline__ unsigned rndb(float f) {          // rounded bits, un-shifted
    unsigned u = __float_as_uint(f);
    return u + 0x7fffu + ((u >> 16) & 1u);
}
// hi/lo bf16 split of a pixel-pair, packed via v_perm.
__device__ __forceinline__ void pack2(float d0, float d1, unsigned &hi, unsigned &lo) {
    unsigned r0 = rndb(d0), r1 = rndb(d1);
    hi = __builtin_amdgcn_perm(r1, r0, 0x07060302u);
    float e0 = d0 - __uint_as_float(r0 & 0xffff0000u);
    float e1 = d1 - __uint_as_float(r1 & 0xffff0000u);
    lo = __builtin_amdgcn_perm(rndb(e1), rndb(e0), 0x07060302u);
}

// ---------------------------------------------------------------------------
// Fused flow-diff + 3x3 conv (bf16-split MFMA) + W-space LIF + spike count.
//
// Barrier-free per-wave tiles (16px x 2 rows).  Round-4 latency surgery:
//  * x prefetch DISTANCE 2 (rb/ra/rc rotation): x[t+4] is loaded at step t,
//    consumed at step t+2's staging -> ~2 full iterations (>= ~900cy HBM
//    latency) of slack instead of 1.
//  * spike-count reduction DEFERRED one step: shfl16 issued at step end,
//    shfl32 + atomic at the NEXT step's top, overlapped with the MFMA block.
//    Removes the serial ~240cy shfl chain from every step.
//  * A elem3 = reused live reg (B k-slots 6,7 are zero in every quad ->
//    elem3 is dead), kills the per-step zero movs.
//  * s_setprio(1) around the MFMA cluster (waves drift -> phase diversity).
//
// W-space LIF (W_t = V_t / beta^t): W += conv_t * beta^-t via the MFMA
// C-operand; spike iff W > thr = ct - b_ch*S_t, reset W -= ct.
// ---------------------------------------------------------------------------
__global__ __launch_bounds__(256, 4) void lif_main(const float* __restrict__ x,
                                                   const float* __restrict__ w_conv,
                                                   const float* __restrict__ b_conv,
                                                   int* __restrict__ spikesum,
                                                   float* __restrict__ out) {
    __shared__ unsigned lds[4][2][2][4 * LROW];  // [wave][buf][plane][row*20+dx] = 5120 B

    const float2* xp2 = (const float2*)x;        // pixel-granular (ci pair)
    const int FRAME2  = BB * HH * WW;            // float2s per time slice

    const int tid  = threadIdx.x;
    const int lane = tid & 63;
    const int wv   = __builtin_amdgcn_readfirstlane(tid >> 6); // uniform 0..3
    const int bx   = blockIdx.x;                 // 0..1 : pixel half
    const int r0   = blockIdx.y << 1;            // first of 2 output rows
    const int bz   = blockIdx.z;                 // batch
    const int q    = lane >> 4;                  // quad
    const int col  = lane & 15;
    const int x0   = (bx << 6) + (wv << 4);      // wave's 16-px slice base
    const int qsh  = q << 3;

    // zero the cross-block-accumulated sr scalar (head adds later in-stream)
    if (bx == 0 && blockIdx.y == 0 && bz == 0 && tid == 0) out[SR_IDX] = 0.f;

    // ---- per-wave staging slots (pair = one pixel, both ci); 72 pairs/wave
    const int  row0 = lane / 18, dx0 = lane - row0 * 18;
    const int  y0s  = r0 - 1 + row0;
    const int  px0s = x0 - 1 + dx0;
    const bool val0 = ((unsigned)y0s < (unsigned)HH) && ((unsigned)px0s < (unsigned)WW);
    const int  off0 = val0 ? (y0s * WW + px0s) : 0;
    const int  ls0  = row0 * LROW + dx0;

    const bool act1 = (lane < 8);
    const int  y1s  = r0 + 2;
    const int  px1s = x0 - 1 + 10 + lane;
    const bool val1 = act1 && ((unsigned)y1s < (unsigned)HH) && ((unsigned)px1s < (unsigned)WW);
    const int  off1 = val1 ? (y1s * WW + px1s) : 0;
    const int  ls1  = 3 * LROW + 10 + lane;

    // A-read base: q==3 reads row0 (finite garbage x B==0 -> exact 0)
    const int rq  = (q < 3) ? q : 0;
    const int rdb = rq * LROW + col;

    // ---- B fragments: k = q*8+j ; q<3: 6 weight taps ; q==3: all zero
    short8 Bh[4], Bl[4];
#pragma unroll
    for (int cg = 0; cg < 4; ++cg) {
        int hi_i[4] = {0, 0, 0, 0}, lo_i[4] = {0, 0, 0, 0};
        if (q < 3) {
#pragma unroll
            for (int j = 0; j < 6; ++j) {
                float w = w_conv[((q * 3 + (j >> 1)) * 2 + (j & 1)) * CHN + cg * 16 + col];
                unsigned hs = rne16(w);
                unsigned ls = rne16(w - b2f(hs));
                hi_i[j >> 1] |= (int)(hs << (16 * (j & 1)));
                lo_i[j >> 1] |= (int)(ls << (16 * (j & 1)));
            }
        }
        int4v hv = {hi_i[0], hi_i[1], hi_i[2], hi_i[3]};
        int4v lv = {lo_i[0], lo_i[1], lo_i[2], lo_i[3]};
        Bh[cg] = __builtin_bit_cast(short8, hv);
        Bl[cg] = __builtin_bit_cast(short8, lv);
    }

    // bias (negated) per cg for the threshold fold
    float nb[4];
#pragma unroll
    for (int cg = 0; cg < 4; ++cg) nb[cg] = -b_conv[cg * 16 + col];

    float4v W0[4], W1[4];                        // membrane (W-space), rows r0, r0+1
#pragma unroll
    for (int cg = 0; cg < 4; ++cg) {
        W0[cg] = (float4v){0.f, 0.f, 0.f, 0.f};
        W1[cg] = (float4v){0.f, 0.f, 0.f, 0.f};
    }

    float ct = 1.0f;                             // beta^-t
    float S  = 1.0f;                             // sum_{tau<=t} beta^-tau
    int* sptp = spikesum + bz * CHN + lane;      // deferred-count cursor (t-1)
    int pendA = 0, pendB = 0;                    // deferred count halves

    // ---- preheader: rb=x[0], ra=x[1], rc=x[2]; stage tile0; rotate; rc=x[3]
    float2 ra_0 = {0.f, 0.f}, rb_0 = {0.f, 0.f}, rc_0 = {0.f, 0.f};
    float2 ra_1 = {0.f, 0.f}, rb_1 = {0.f, 0.f}, rc_1 = {0.f, 0.f};
    const float2* xb = xp2 + bz * HH * WW;
    if (val0) { rb_0 = xb[off0]; ra_0 = xb[FRAME2 + off0]; rc_0 = xb[2 * FRAME2 + off0]; }
    if (val1) { rb_1 = xb[off1]; ra_1 = xb[FRAME2 + off1]; rc_1 = xb[2 * FRAME2 + off1]; }
    {
        unsigned* hiW = &lds[wv][0][0][0];
        unsigned* loW = &lds[wv][0][1][0];
        {
            float d0 = (ra_0.x - rb_0.x), d1 = (ra_0.y - rb_0.y);
            unsigned hw, lw; pack2(d0, d1, hw, lw);
            hiW[ls0] = hw; loW[ls0] = lw;
        }
        if (act1) {
            float d0 = (ra_1.x - rb_1.x), d1 = (ra_1.y - rb_1.y);
            unsigned hw, lw; pack2(d0, d1, hw, lw);
            hiW[ls1] = hw; loW[ls1] = lw;
        }
        rb_0 = ra_0; ra_0 = rc_0;
        rb_1 = ra_1; ra_1 = rc_1;
        if (val0) rc_0 = xb[3 * FRAME2 + off0];
        if (val1) rc_1 = xb[3 * FRAME2 + off1];
    }
    const float2* xn = xb + 4 * FRAME2;          // prefetch cursor: slice t+4

#define STEP(T_, CUR, NXT) do {                                                 \
    /* 1. A-fragment reads (data staged one iteration ago) */                   \
    const unsigned* hiR = &lds[wv][CUR][0][0] + rdb;                            \
    const unsigned* loR = &lds[wv][CUR][1][0] + rdb;                            \
    unsigned h0 = hiR[0], h1 = hiR[1], h2 = hiR[2];                             \
    unsigned h3 = hiR[LROW], h4 = hiR[LROW + 1], h5 = hiR[LROW + 2];            \
    unsigned l0 = loR[0], l1 = loR[1], l2 = loR[2];                             \
    unsigned l3 = loR[LROW], l4 = loR[LROW + 1], l5 = loR[LROW + 2];            \
    /* 2. deferred count: finish step T_-1 (shfl32 overlaps MFMA below) */      \
    int cp1_ = 0, sh2_ = 0;                                                     \
    if ((T_) > 0) { cp1_ = pendA + pendB; sh2_ = __shfl_xor(cp1_, 32); }        \
    /* 3. stage tile T_+1 into the other buffer (overlaps read latency) */      \
    float ctn = ct * INVB;                                                      \
    if ((T_) + 1 < TS) {                                                        \
        unsigned* hiW = &lds[wv][NXT][0][0];                                    \
        unsigned* loW = &lds[wv][NXT][1][0];                                    \
        {                                                                       \
            float d0 = (ra_0.x - rb_0.x) * ctn;                                 \
            float d1 = (ra_0.y - rb_0.y) * ctn;                                 \
            unsigned hw, lw; pack2(d0, d1, hw, lw);                             \
            hiW[ls0] = hw; loW[ls0] = lw;                                       \
        }                                                                       \
        if (act1) {                                                             \
            float d0 = (ra_1.x - rb_1.x) * ctn;                                 \
            float d1 = (ra_1.y - rb_1.y) * ctn;                                 \
            unsigned hw, lw; pack2(d0, d1, hw, lw);                             \
            hiW[ls1] = hw; loW[ls1] = lw;                                       \
        }                                                                       \
        rb_0 = ra_0; ra_0 = rc_0;                                               \
        rb_1 = ra_1; ra_1 = rc_1;                                               \
        if ((T_) + 4 < TT) {                                                    \
            if (val0) rc_0 = xn[off0];                                          \
            if (val1) rc_1 = xn[off1];                                          \
            xn += FRAME2;                                                       \
        }                                                                       \
    }                                                                           \
    /* 4. assemble A (elem3 = dead reg: B k=6,7 slots are zero) */              \
    int4v a0h = {(int)h0, (int)h1, (int)h2, (int)h0};                           \
    int4v a0l = {(int)l0, (int)l1, (int)l2, (int)l0};                           \
    int4v a1h = {(int)h3, (int)h4, (int)h5, (int)h3};                           \
    int4v a1l = {(int)l3, (int)l4, (int)l5, (int)l3};                           \
    short8 A0h = __builtin_bit_cast(short8, a0h);                               \
    short8 A0l = __builtin_bit_cast(short8, a0l);                               \
    short8 A1h = __builtin_bit_cast(short8, a1h);                               \
    short8 A1l = __builtin_bit_cast(short8, a1l);                               \
    /* 5. 3-pass MFMA (8 independent chains per pass) */                        \
    __builtin_amdgcn_s_setprio(1);                                              \
    _Pragma("unroll")                                                           \
    for (int cg = 0; cg < 4; ++cg) {                                            \
        W0[cg] = __builtin_amdgcn_mfma_f32_16x16x32_bf16(A0h, Bh[cg], W0[cg], 0, 0, 0); \
        W1[cg] = __builtin_amdgcn_mfma_f32_16x16x32_bf16(A1h, Bh[cg], W1[cg], 0, 0, 0); \
    }                                                                           \
    _Pragma("unroll")                                                           \
    for (int cg = 0; cg < 4; ++cg) {                                            \
        W0[cg] = __builtin_amdgcn_mfma_f32_16x16x32_bf16(A0l, Bh[cg], W0[cg], 0, 0, 0); \
        W1[cg] = __builtin_amdgcn_mfma_f32_16x16x32_bf16(A1l, Bh[cg], W1[cg], 0, 0, 0); \
    }                                                                           \
    _Pragma("unroll")                                                           \
    for (int cg = 0; cg < 4; ++cg) {                                            \
        W0[cg] = __builtin_amdgcn_mfma_f32_16x16x32_bf16(A0h, Bl[cg], W0[cg], 0, 0, 0); \
        W1[cg] = __builtin_amdgcn_mfma_f32_16x16x32_bf16(A1h, Bl[cg], W1[cg], 0, 0, 0); \
    }                                                                           \
    __builtin_amdgcn_s_setprio(0);                                              \
    /* 6. deferred atomic for step T_-1 (sh2_ latency buried under MFMA) */     \
    if ((T_) > 0) {                                                             \
        atomicAdd(sptp, ((cp1_ + sh2_) >> qsh) & 255);                          \
        sptp += BB * CHN;                                                       \
    }                                                                           \
    /* 7. LIF + count; hand off half-reduced count to next step */              \
    int cpack = 0;                                                              \
    _Pragma("unroll")                                                           \
    for (int cg = 0; cg < 4; ++cg) {                                            \
        float thr = fmaf(nb[cg], S, ct);                                        \
        float4v w0 = W0[cg], w1 = W1[cg];                                       \
        int c = 0;                                                              \
        _Pragma("unroll")                                                       \
        for (int r = 0; r < 4; ++r) {                                           \
            float v0 = w0[r]; bool s0 = v0 > thr;                               \
            w0[r] = s0 ? (v0 - ct) : v0; c += s0;                               \
            float v1 = w1[r]; bool s1 = v1 > thr;                               \
            w1[r] = s1 ? (v1 - ct) : v1; c += s1;                               \
        }                                                                       \
        W0[cg] = w0; W1[cg] = w1;                                               \
        cpack |= c << (8 * cg);                                                 \
    }                                                                           \
    pendA = cpack;                                                              \
    pendB = __shfl_xor(cpack, 16);                                              \
    ct = ctn; S += ctn;                                                         \
} while (0)

    STEP(0, 0, 1);
#pragma unroll 1
    for (int t = 1; t + 1 < TS; t += 2) {        // covers t = 1..18
        STEP(t, 1, 0);
        STEP(t + 1, 0, 1);
    }
#undef STEP

    // epilogue: flush the deferred count for t = TS-1
    {
        int cp1 = pendA + pendB;
        int cp2 = cp1 + __shfl_xor(cp1, 32);
        atomicAdd(sptp, (cp2 >> qsh) & 255);
    }
}

// ---------------------------------------------------------------------------
// head: one block per batch b. Computes logits[t][b][:] directly, readout[b][:]
// locally (no atomics), and one atomicAdd per block into the sr scalar
// (zeroed by lif_main). No d_out memset needed.
// ---------------------------------------------------------------------------
__global__ __launch_bounds__(256) void head_kernel(const int* __restrict__ spikesum,
                                                   const float* __restrict__ w_head,
                                                   const float* __restrict__ b_head,
                                                   float* __restrict__ out) {
    const int b    = blockIdx.x;
    const int lane = threadIdx.x & 63;
    const int wv   = threadIdx.x >> 6;           // 0..3, wave handles t = wv, wv+4, ...
    __shared__ float red[4][NOUT + 1];

    float wrow[NOUT];
#pragma unroll
    for (int o = 0; o < NOUT; ++o) wrow[o] = w_head[lane * NOUT + o] * (1.f / (HH * WW));

    float racc[NOUT];
#pragma unroll
    for (int o = 0; o < NOUT; ++o) racc[o] = 0.f;
    float ftot = 0.f;

    for (int t = wv; t < TS; t += 4) {
        float s = (float)spikesum[(t * BB + b) * CHN + lane];
        float acc[NOUT];
#pragma unroll
        for (int o = 0; o < NOUT; ++o) acc[o] = s * wrow[o];
        float tt = s;
#pragma unroll
        for (int off = 32; off > 0; off >>= 1) {
#pragma unroll
            for (int o = 0; o < NOUT; ++o) acc[o] += __shfl_down(acc[o], off);
            tt += __shfl_down(tt, off);
        }
        if (lane == 0) {
#pragma unroll
            for (int o = 0; o < NOUT; ++o) {
                float lg = acc[o] + b_head[o];
                out[BB * NOUT + (t * BB + b) * NOUT + o] = lg;
                racc[o] += lg;
            }
            ftot += tt;
        }
    }
    if (lane == 0) {
#pragma unroll
        for (int o = 0; o < NOUT; ++o) red[wv][o] = racc[o];
        red[wv][NOUT] = ftot;
    }
    __syncthreads();
    if (threadIdx.x < NOUT) {
        float r = red[0][threadIdx.x] + red[1][threadIdx.x] +
                  red[2][threadIdx.x] + red[3][threadIdx.x];
        out[b * NOUT + threadIdx.x] = r * (1.f / TS);
    } else if (threadIdx.x == NOUT) {
        float ft = red[0][NOUT] + red[1][NOUT] + red[2][NOUT] + red[3][NOUT];
        atomicAdd(&out[SR_IDX], ft * (1.f / ((float)TS * BB * HH * WW * CHN)));
    }
}

// ---------------------------------------------------------------------------
extern "C" void kernel_launch(void* const* d_in, const int* in_sizes, int n_in,
                              void* d_out, int out_size, void* d_ws, size_t ws_size,
                              hipStream_t stream) {
    (void)in_sizes; (void)n_in; (void)ws_size; (void)out_size;
    const float* x      = (const float*)d_in[0];
    const float* w_conv = (const float*)d_in[1];
    const float* b_conv = (const float*)d_in[2];
    const float* w_head = (const float*)d_in[3];
    const float* b_head = (const float*)d_in[4];
    float* out      = (float*)d_out;
    int*   spikesum = (int*)d_ws;

    (void)hipMemsetAsync(d_ws, 0, SPIKESUM_BYTES, stream);

    lif_main<<<dim3(2, HH / 2, BB), 256, 0, stream>>>(x, w_conv, b_conv, spikesum, out);
    head_kernel<<<dim3(BB), 256, 0, stream>>>(spikesum, w_head, b_head, out);
}

// Round 5
// 164.200 us; speedup vs baseline: 1.2582x; 1.1585x over previous
//
#include <hip/hip_runtime.h>
#include <hip/hip_bf16.h>

// Problem constants
#define TT   20
#define TS   19          // T-1 steps
#define BB   16
#define HH   128
#define WW   128
#define CINN 2
#define CHN  64
#define NOUT 10
#define BETA 0.9f
#define INVB (1.0f / BETA)
#define THRV 1.0f

#define NCHUNK 5                              // ceil(19/4) byte-packed t-chunks
#define NPB    128                            // partial blocks per batch (64 by x 2 bx)
#define SR_IDX (BB*NOUT + TS*BB*NOUT)         // scalar spike-rate slot in out
// ws layout: int ws[BB][NCHUNK][NPB][CHN]  = 16*5*128*64*4 B = 2.62 MB

#define LROW  20                              // dwords per staged row (18 + 2 pad)

typedef __attribute__((ext_vector_type(8))) short short8;
typedef __attribute__((ext_vector_type(4))) float float4v;
typedef __attribute__((ext_vector_type(4))) int   int4v;

// round-to-nearest-even fp32 -> bf16 bits
__device__ __forceinline__ unsigned rne16(float f) {
    unsigned u = __float_as_uint(f);
    return (u + 0x7fffu + ((u >> 16) & 1u)) >> 16;
}
__device__ __forceinline__ float b2f(unsigned us) { return __uint_as_float(us << 16); }
__device__ __forceinline__ unsigned rndb(float f) {          // rounded bits, un-shifted
    unsigned u = __float_as_uint(f);
    return u + 0x7fffu + ((u >> 16) & 1u);
}
// hi/lo bf16 split of a pixel-pair, packed via v_perm.
__device__ __forceinline__ void pack2(float d0, float d1, unsigned &hi, unsigned &lo) {
    unsigned r0 = rndb(d0), r1 = rndb(d1);
    hi = __builtin_amdgcn_perm(r1, r0, 0x07060302u);
    float e0 = d0 - __uint_as_float(r0 & 0xffff0000u);
    float e1 = d1 - __uint_as_float(r1 & 0xffff0000u);
    lo = __builtin_amdgcn_perm(rndb(e1), rndb(e0), 0x07060302u);
}

// ---------------------------------------------------------------------------
// Fused flow-diff + 3x3 conv (bf16-split MFMA) + W-space LIF + spike count.
//
// Round-5: ZERO GLOBAL ATOMICS in the main loop. The old per-step spikesum
// atomicAdd (9.95M lane-atomics) generated 39.8 MB of HBM writes AND poisoned
// vmcnt: vmcnt retires in issue order, so prefetch loads issued after a slow
// atomic couldn't satisfy their s_waitcnt until the atomic drained.  Counts
// are now byte-packed in a register (compile-time byte positions via a
// 4-step-chunk loop), merged across the block's 4 waves with ONE LDS atomic
// per chunk, and written as per-block partials with plain coalesced stores.
// Head reduces the 128 partials per (t,b,ch).
//
// Retained: barrier-free drifting waves (except init/fini), distance-2 x
// prefetch, 1-step-deferred shfl reduction, independent MFMA chains,
// dead-elem3 A fragments, setprio around MFMA.
// W-space LIF (W_t = V_t / beta^t): W += conv_t*beta^-t via MFMA C-operand;
// spike iff W > thr = ct - b_ch*S_t, reset W -= ct.
// ---------------------------------------------------------------------------
__global__ __launch_bounds__(256, 4) void lif_main(const float* __restrict__ x,
                                                   const float* __restrict__ w_conv,
                                                   const float* __restrict__ b_conv,
                                                   int* __restrict__ ws,
                                                   float* __restrict__ out) {
    __shared__ unsigned lds[4][2][2][4 * LROW];  // [wave][buf][plane][row*20+dx] = 5120 B
    __shared__ int lds_cnt[NCHUNK][CHN];          // block-combined packed counts, 1280 B

    const float2* xp2 = (const float2*)x;        // pixel-granular (ci pair)
    const int FRAME2  = BB * HH * WW;            // float2s per time slice

    const int tid  = threadIdx.x;
    const int lane = tid & 63;
    const int wv   = __builtin_amdgcn_readfirstlane(tid >> 6); // uniform 0..3
    const int bx   = blockIdx.x;                 // 0..1 : pixel half
    const int r0   = blockIdx.y << 1;            // first of 2 output rows
    const int bz   = blockIdx.z;                 // batch
    const int q    = lane >> 4;                  // quad
    const int col  = lane & 15;
    const int x0   = (bx << 6) + (wv << 4);      // wave's 16-px slice base
    const int qsh  = q << 3;

    // zero readout + sr slots (head atomics accumulate later, same stream)
    if (bx == 0 && blockIdx.y == 0 && bz == 0) {
        if (tid < BB * NOUT) out[tid] = 0.f;
        else if (tid == BB * NOUT) out[SR_IDX] = 0.f;
    }

    // zero the block count buffer, then one alignment barrier
    if (tid < NCHUNK * CHN - 256) ((int*)lds_cnt)[256 + tid] = 0;
    ((int*)lds_cnt)[tid] = 0;
    __syncthreads();

    // ---- per-wave staging slots (pair = one pixel, both ci); 72 pairs/wave
    const int  row0 = lane / 18, dx0 = lane - row0 * 18;
    const int  y0s  = r0 - 1 + row0;
    const int  px0s = x0 - 1 + dx0;
    const bool val0 = ((unsigned)y0s < (unsigned)HH) && ((unsigned)px0s < (unsigned)WW);
    const int  off0 = val0 ? (y0s * WW + px0s) : 0;
    const int  ls0  = row0 * LROW + dx0;

    const bool act1 = (lane < 8);
    const int  y1s  = r0 + 2;
    const int  px1s = x0 - 1 + 10 + lane;
    const bool val1 = act1 && ((unsigned)y1s < (unsigned)HH) && ((unsigned)px1s < (unsigned)WW);
    const int  off1 = val1 ? (y1s * WW + px1s) : 0;
    const int  ls1  = 3 * LROW + 10 + lane;

    // A-read base: q==3 reads row0 (finite garbage x B==0 -> exact 0)
    const int rq  = (q < 3) ? q : 0;
    const int rdb = rq * LROW + col;

    // ---- B fragments: k = q*8+j ; q<3: 6 weight taps ; q==3: all zero
    short8 Bh[4], Bl[4];
#pragma unroll
    for (int cg = 0; cg < 4; ++cg) {
        int hi_i[4] = {0, 0, 0, 0}, lo_i[4] = {0, 0, 0, 0};
        if (q < 3) {
#pragma unroll
            for (int j = 0; j < 6; ++j) {
                float w = w_conv[((q * 3 + (j >> 1)) * 2 + (j & 1)) * CHN + cg * 16 + col];
                unsigned hs = rne16(w);
                unsigned ls = rne16(w - b2f(hs));
                hi_i[j >> 1] |= (int)(hs << (16 * (j & 1)));
                lo_i[j >> 1] |= (int)(ls << (16 * (j & 1)));
            }
        }
        int4v hv = {hi_i[0], hi_i[1], hi_i[2], hi_i[3]};
        int4v lv = {lo_i[0], lo_i[1], lo_i[2], lo_i[3]};
        Bh[cg] = __builtin_bit_cast(short8, hv);
        Bl[cg] = __builtin_bit_cast(short8, lv);
    }

    // bias (negated) per cg for the threshold fold
    float nb[4];
#pragma unroll
    for (int cg = 0; cg < 4; ++cg) nb[cg] = -b_conv[cg * 16 + col];

    float4v W0[4], W1[4];                        // membrane (W-space), rows r0, r0+1
#pragma unroll
    for (int cg = 0; cg < 4; ++cg) {
        W0[cg] = (float4v){0.f, 0.f, 0.f, 0.f};
        W1[cg] = (float4v){0.f, 0.f, 0.f, 0.f};
    }

    float ct = 1.0f;                             // beta^-t
    float S  = 1.0f;                             // sum_{tau<=t} beta^-tau
    int pendA = 0, pendB = 0;                    // deferred count halves
    unsigned cur = 0;                            // byte-packed counts, current chunk

    // ---- preheader: rb=x[0], ra=x[1], rc=x[2]; stage tile0; rotate; rc=x[3]
    float2 ra_0 = {0.f, 0.f}, rb_0 = {0.f, 0.f}, rc_0 = {0.f, 0.f};
    float2 ra_1 = {0.f, 0.f}, rb_1 = {0.f, 0.f}, rc_1 = {0.f, 0.f};
    const float2* xb = xp2 + bz * HH * WW;
    if (val0) { rb_0 = xb[off0]; ra_0 = xb[FRAME2 + off0]; rc_0 = xb[2 * FRAME2 + off0]; }
    if (val1) { rb_1 = xb[off1]; ra_1 = xb[FRAME2 + off1]; rc_1 = xb[2 * FRAME2 + off1]; }
    {
        unsigned* hiW = &lds[wv][0][0][0];
        unsigned* loW = &lds[wv][0][1][0];
        {
            float d0 = (ra_0.x - rb_0.x), d1 = (ra_0.y - rb_0.y);
            unsigned hw, lw; pack2(d0, d1, hw, lw);
            hiW[ls0] = hw; loW[ls0] = lw;
        }
        if (act1) {
            float d0 = (ra_1.x - rb_1.x), d1 = (ra_1.y - rb_1.y);
            unsigned hw, lw; pack2(d0, d1, hw, lw);
            hiW[ls1] = hw; loW[ls1] = lw;
        }
        rb_0 = ra_0; ra_0 = rc_0;
        rb_1 = ra_1; ra_1 = rc_1;
        if (val0) rc_0 = xb[3 * FRAME2 + off0];
        if (val1) rc_1 = xb[3 * FRAME2 + off1];
    }
    const float2* xn = xb + 4 * FRAME2;          // prefetch cursor: slice t+4

// STEP: one LIF time step. DPOS = byte position of the deferred (T-1) count
// (compile-time). DODEF: resolve deferred count. DOFLUSH/CK: LDS-merge the
// completed chunk dword. DOSTAGE/DOPREF: stage tile T+1 / prefetch x[T+4].
#define STEP(T_, CURB, NXTB, DPOS, DODEF, DOFLUSH, CK, DOSTAGE, DOPREF) do {    \
    const unsigned* hiR = &lds[wv][CURB][0][0] + rdb;                           \
    const unsigned* loR = &lds[wv][CURB][1][0] + rdb;                           \
    unsigned h0 = hiR[0], h1 = hiR[1], h2 = hiR[2];                             \
    unsigned h3 = hiR[LROW], h4 = hiR[LROW + 1], h5 = hiR[LROW + 2];            \
    unsigned l0 = loR[0], l1 = loR[1], l2 = loR[2];                             \
    unsigned l3 = loR[LROW], l4 = loR[LROW + 1], l5 = loR[LROW + 2];            \
    int cp1_ = 0, sh2_ = 0;                                                     \
    if (DODEF) { cp1_ = pendA + pendB; sh2_ = __shfl_xor(cp1_, 32); }           \
    float ctn = ct * INVB;                                                      \
    if (DOSTAGE) {                                                              \
        unsigned* hiW = &lds[wv][NXTB][0][0];                                   \
        unsigned* loW = &lds[wv][NXTB][1][0];                                   \
        {                                                                       \
            float d0 = (ra_0.x - rb_0.x) * ctn;                                 \
            float d1 = (ra_0.y - rb_0.y) * ctn;                                 \
            unsigned hw, lw; pack2(d0, d1, hw, lw);                             \
            hiW[ls0] = hw; loW[ls0] = lw;                                       \
        }                                                                       \
        if (act1) {                                                             \
            float d0 = (ra_1.x - rb_1.x) * ctn;                                 \
            float d1 = (ra_1.y - rb_1.y) * ctn;                                 \
            unsigned hw, lw; pack2(d0, d1, hw, lw);                             \
            hiW[ls1] = hw; loW[ls1] = lw;                                       \
        }                                                                       \
        rb_0 = ra_0; ra_0 = rc_0;                                               \
        rb_1 = ra_1; ra_1 = rc_1;                                               \
        if (DOPREF) {                                                           \
            if (val0) rc_0 = xn[off0];                                          \
            if (val1) rc_1 = xn[off1];                                          \
            xn += FRAME2;                                                       \
        }                                                                       \
    }                                                                           \
    int4v a0h = {(int)h0, (int)h1, (int)h2, (int)h0};                           \
    int4v a0l = {(int)l0, (int)l1, (int)l2, (int)l0};                           \
    int4v a1h = {(int)h3, (int)h4, (int)h5, (int)h3};                           \
    int4v a1l = {(int)l3, (int)l4, (int)l5, (int)l3};                           \
    short8 A0h = __builtin_bit_cast(short8, a0h);                               \
    short8 A0l = __builtin_bit_cast(short8, a0l);                               \
    short8 A1h = __builtin_bit_cast(short8, a1h);                               \
    short8 A1l = __builtin_bit_cast(short8, a1l);                               \
    __builtin_amdgcn_s_setprio(1);                                              \
    _Pragma("unroll")                                                           \
    for (int cg = 0; cg < 4; ++cg) {                                            \
        W0[cg] = __builtin_amdgcn_mfma_f32_16x16x32_bf16(A0h, Bh[cg], W0[cg], 0, 0, 0); \
        W1[cg] = __builtin_amdgcn_mfma_f32_16x16x32_bf16(A1h, Bh[cg], W1[cg], 0, 0, 0); \
    }                                                                           \
    _Pragma("unroll")                                                           \
    for (int cg = 0; cg < 4; ++cg) {                                            \
        W0[cg] = __builtin_amdgcn_mfma_f32_16x16x32_bf16(A0l, Bh[cg], W0[cg], 0, 0, 0); \
        W1[cg] = __builtin_amdgcn_mfma_f32_16x16x32_bf16(A1l, Bh[cg], W1[cg], 0, 0, 0); \
    }                                                                           \
    _Pragma("unroll")                                                           \
    for (int cg = 0; cg < 4; ++cg) {                                            \
        W0[cg] = __builtin_amdgcn_mfma_f32_16x16x32_bf16(A0h, Bl[cg], W0[cg], 0, 0, 0); \
        W1[cg] = __builtin_amdgcn_mfma_f32_16x16x32_bf16(A1h, Bl[cg], W1[cg], 0, 0, 0); \
    }                                                                           \
    __builtin_amdgcn_s_setprio(0);                                              \
    if (DODEF) {                                                                \
        unsigned cnt_ = ((unsigned)(cp1_ + sh2_) >> qsh) & 255u;                \
        cur |= cnt_ << (8 * (DPOS));                                            \
        if (DOFLUSH) { atomicAdd(&lds_cnt[CK][lane], (int)cur); cur = 0u; }     \
    }                                                                           \
    int cpack = 0;                                                              \
    _Pragma("unroll")                                                           \
    for (int cg = 0; cg < 4; ++cg) {                                            \
        float thr = fmaf(nb[cg], S, ct);                                        \
        float4v w0 = W0[cg], w1 = W1[cg];                                       \
        int c = 0;                                                              \
        _Pragma("unroll")                                                       \
        for (int r = 0; r < 4; ++r) {                                           \
            float v0 = w0[r]; bool s0 = v0 > thr;                               \
            w0[r] = s0 ? (v0 - ct) : v0; c += s0;                               \
            float v1 = w1[r]; bool s1 = v1 > thr;                               \
            w1[r] = s1 ? (v1 - ct) : v1; c += s1;                               \
        }                                                                       \
        W0[cg] = w0; W1[cg] = w1;                                               \
        cpack |= c << (8 * cg);                                                 \
    }                                                                           \
    pendA = cpack;                                                              \
    pendB = __shfl_xor(cpack, 16);                                              \
    ct = ctn; S += ctn;                                                         \
} while (0)

#pragma unroll 1
    for (int c = 0; c < 4; ++c) {                // steps 0..15
        STEP(4 * c + 0, 0, 1, 3, (c > 0), (c > 0), (c - 1), 1, 1);
        STEP(4 * c + 1, 1, 0, 0, 1, 0, 0, 1, 1);
        STEP(4 * c + 2, 0, 1, 1, 1, 0, 0, 1, 1);
        STEP(4 * c + 3, 1, 0, 2, 1, 0, 0, 1, 1);
    }
    STEP(16, 0, 1, 3, 1, 1, 3, 1, 0);            // resolves 15, flushes chunk3
    STEP(17, 1, 0, 0, 1, 0, 0, 1, 0);
    STEP(18, 0, 1, 1, 1, 0, 0, 0, 0);
#undef STEP

    // flush step 18's count (byte 2) and chunk 4
    {
        int cp1 = pendA + pendB;
        int cp2 = cp1 + __shfl_xor(cp1, 32);
        unsigned cnt = ((unsigned)cp2 >> qsh) & 255u;
        cur |= cnt << 16;
        atomicAdd(&lds_cnt[4][lane], (int)cur);
    }
    __syncthreads();

    // write block partials: ws[bz][k][pb][ch], plain coalesced stores
    {
        const int pb = (blockIdx.y << 1) | bx;   // 0..127
        const int k0 = tid >> 6, ch = tid & 63;
        ws[((bz * NCHUNK + k0) * NPB + pb) * CHN + ch] = lds_cnt[k0][ch];
        if (tid < CHN)
            ws[((bz * NCHUNK + 4) * NPB + pb) * CHN + tid] = lds_cnt[4][tid];
    }
}

// ---------------------------------------------------------------------------
// head: block per (t,b), one wave. Reduces 128 byte-packed partials per
// channel, then logits = (count/16384) @ w_head + b_head; readout and sr
// accumulate via a few thousand tiny atomics (slots zeroed by lif_main).
// ---------------------------------------------------------------------------
__global__ __launch_bounds__(64) void head_kernel(const int* __restrict__ ws,
                                                  const float* __restrict__ w_head,
                                                  const float* __restrict__ b_head,
                                                  float* __restrict__ out) {
    const int t = blockIdx.x, b = blockIdx.y, ch = threadIdx.x;
    const int k = t >> 2, sh = (t & 3) << 3;
    const int* base = ws + ((b * NCHUNK + k) * NPB) * CHN + ch;

    int cnt = 0;
#pragma unroll 8
    for (int p = 0; p < NPB; ++p) cnt += (base[p * CHN] >> sh) & 255;

    const float s = (float)cnt * (1.f / (HH * WW));
    float acc[NOUT];
#pragma unroll
    for (int o = 0; o < NOUT; ++o) acc[o] = s * w_head[ch * NOUT + o];
    float tt = (float)cnt;
#pragma unroll
    for (int off = 32; off > 0; off >>= 1) {
#pragma unroll
        for (int o = 0; o < NOUT; ++o) acc[o] += __shfl_down(acc[o], off);
        tt += __shfl_down(tt, off);
    }
    if (ch == 0) {
#pragma unroll
        for (int o = 0; o < NOUT; ++o) {
            float lg = acc[o] + b_head[o];
            out[BB * NOUT + (t * BB + b) * NOUT + o] = lg;
            atomicAdd(&out[b * NOUT + o], lg * (1.f / TS));
        }
        atomicAdd(&out[SR_IDX], tt * (1.f / ((float)TS * BB * HH * WW * CHN)));
    }
}

// ---------------------------------------------------------------------------
extern "C" void kernel_launch(void* const* d_in, const int* in_sizes, int n_in,
                              void* d_out, int out_size, void* d_ws, size_t ws_size,
                              hipStream_t stream) {
    (void)in_sizes; (void)n_in; (void)ws_size; (void)out_size;
    const float* x      = (const float*)d_in[0];
    const float* w_conv = (const float*)d_in[1];
    const float* b_conv = (const float*)d_in[2];
    const float* w_head = (const float*)d_in[3];
    const float* b_head = (const float*)d_in[4];
    float* out = (float*)d_out;
    int*   ws  = (int*)d_ws;

    lif_main<<<dim3(2, HH / 2, BB), 256, 0, stream>>>(x, w_conv, b_conv, ws, out);
    head_kernel<<<dim3(TS, BB), 64, 0, stream>>>(ws, w_head, b_head, out);
}